// Round 11
// baseline (258.110 us; speedup 1.0000x reference)
//
#include <hip/hip_runtime.h>

#define N_NODES 50000
#define N_EDGES 800000
#define NBUCKET 196           // ceil(N_NODES / 256); bucket b = dst in [b*256,(b+1)*256)
#define EPB 4096              // edges per block in bucket_count / partition (16/thread)
#define EDGE_BLKS ((N_EDGES + EPB - 1) / EPB)  // 196

__device__ __forceinline__ int wave_incl_scan(int v, int lane) {
#pragma unroll
    for (int off = 1; off < 64; off <<= 1) {
        int t = __shfl_up(v, off, 64);
        if (lane >= off) v += t;
    }
    return v;
}

// ---------- CSR build via bucket counting sort ----------

__global__ __launch_bounds__(256) void bucket_count(const int* __restrict__ dst,
                                                    int* __restrict__ bcnt, int nedges) {
    __shared__ int h[NBUCKET];
    for (int i = threadIdx.x; i < NBUCKET; i += 256) h[i] = 0;
    __syncthreads();
    const int eb = blockIdx.x * EPB;
#pragma unroll
    for (int i = 0; i < 16; ++i) {
        int e = eb + i * 256 + threadIdx.x;
        if (e < nedges) atomicAdd(&h[dst[e] >> 8], 1);
    }
    __syncthreads();
    for (int i = threadIdx.x; i < NBUCKET; i += 256)
        if (h[i]) atomicAdd(&bcnt[i], h[i]);
}

__global__ __launch_bounds__(256) void bucket_scan(const int* __restrict__ bcnt,
                                                   int* __restrict__ bbase,
                                                   int* __restrict__ bcursor, int nb) {
    const int i = threadIdx.x;
    const int lane = i & 63;
    const int w = i >> 6;
    int v = (i < nb) ? bcnt[i] : 0;
    int s = wave_incl_scan(v, lane);
    __shared__ int ws[4];
    if (lane == 63) ws[w] = s;
    __syncthreads();
    int add = 0;
#pragma unroll
    for (int k = 0; k < 4; ++k)
        if (k < w) add += ws[k];
    if (i < nb) {
        int excl = s + add - v;
        bbase[i] = excl;
        bcursor[i] = excl;
    }
}

__global__ __launch_bounds__(256) void partition_kernel(const int* __restrict__ src,
                                                        const int* __restrict__ dst,
                                                        int* __restrict__ bcursor,
                                                        int* __restrict__ etmp, int nedges) {
    __shared__ int h[NBUCKET];
    __shared__ int rbase[NBUCKET];
    for (int i = threadIdx.x; i < NBUCKET; i += 256) h[i] = 0;
    __syncthreads();

    const int eb = blockIdx.x * EPB;
    int d[16], s[16];
    bool ok[16];
#pragma unroll
    for (int i = 0; i < 16; ++i) {
        int e = eb + i * 256 + threadIdx.x;
        ok[i] = e < nedges;
        d[i] = ok[i] ? dst[e] : 0;
        s[i] = ok[i] ? src[e] : 0;
        if (ok[i]) atomicAdd(&h[d[i] >> 8], 1);
    }
    __syncthreads();
    for (int i = threadIdx.x; i < NBUCKET; i += 256) {
        rbase[i] = h[i] ? atomicAdd(&bcursor[i], h[i]) : 0;
        h[i] = 0;  // reuse as local cursor
    }
    __syncthreads();
#pragma unroll
    for (int i = 0; i < 16; ++i) {
        if (ok[i]) {
            int b = d[i] >> 8;
            int pos = rbase[b] + atomicAdd(&h[b], 1);
            etmp[pos] = ((d[i] & 255) << 16) | s[i];
        }
    }
}

__global__ __launch_bounds__(256) void bucket_build(const int* __restrict__ etmp,
                                                    const int* __restrict__ bbase,
                                                    int* __restrict__ rowptr,
                                                    int* __restrict__ esrc,
                                                    float* __restrict__ norm,
                                                    int nnodes, int nbuckets, int nedges) {
    const int b = blockIdx.x;
    const int nodebase = b * 256;
    const int nloc = min(256, nnodes - nodebase);
    const int ebeg = bbase[b];
    const int eend = (b + 1 < nbuckets) ? bbase[b + 1] : nedges;

    __shared__ int h[256];
    __shared__ int cur[256];
    h[threadIdx.x] = 0;
    __syncthreads();

    for (int e = ebeg + threadIdx.x; e < eend; e += 256)
        atomicAdd(&h[etmp[e] >> 16], 1);
    __syncthreads();

    const int lane = threadIdx.x & 63;
    const int w = threadIdx.x >> 6;
    int v = h[threadIdx.x];
    int sc = wave_incl_scan(v, lane);
    __shared__ int ws[4];
    if (lane == 63) ws[w] = sc;
    __syncthreads();
    int add = 0;
#pragma unroll
    for (int k = 0; k < 4; ++k)
        if (k < w) add += ws[k];
    const int excl = sc + add - v;

    if (threadIdx.x < nloc) {
        rowptr[nodebase + threadIdx.x] = ebeg + excl;
        norm[nodebase + threadIdx.x] = v > 0 ? rsqrtf((float)v) : 0.0f;
        if (nodebase + threadIdx.x == nnodes - 1) rowptr[nnodes] = ebeg + excl + v;
    }
    cur[threadIdx.x] = excl;
    __syncthreads();

    for (int e = ebeg + threadIdx.x; e < eend; e += 256) {
        int rec = etmp[e];
        int pos = ebeg + atomicAdd(&cur[rec >> 16], 1);
        esrc[pos] = rec & 0xFFFF;
    }
}

// ---------- GEMM with output row-scale, W staged in LDS (64-col half-blocks) ----------
// C_sliced[s][r][c] = norm[r] * sum_k X[r,k] * W[k, s*32+c]
// Block covers 128 rows x 64 cols; Wlds = 32 KB -> 4-5 blocks/CU for latency hiding.
// Output: OUT/32 slabs of [nrows x 32] floats (slice-major, 128 B rows).
template <int OUT>
__global__ __launch_bounds__(256, 4) void gemm_rownorm(const float* __restrict__ X,
                                                       const float* __restrict__ W,
                                                       const float* __restrict__ norm,
                                                       float* __restrict__ C, int nrows) {
    constexpr int NHALF = OUT / 64;          // 2 for OUT=128, 1 for OUT=64
    const int half = (NHALF > 1) ? (blockIdx.x % NHALF) : 0;
    const int rowblk = blockIdx.x / NHALF;

    __shared__ float Wlds[128 * 64];  // 32 KB

    const int t = threadIdx.x;

    // Stage this half's W columns: W[k][half*64 .. half*64+63], 2048 float4s.
    {
        const float4* __restrict__ Wg = reinterpret_cast<const float4*>(W);
        float4* Wl = reinterpret_cast<float4*>(Wlds);
#pragma unroll
        for (int s = 0; s < 8; ++s) {
            int idx = s * 256 + t;          // 0..2047
            int k  = idx >> 4;              // W row
            int cg = idx & 15;              // float4 within 64 cols
            Wl[idx] = Wg[k * (OUT / 4) + half * 16 + cg];
        }
    }
    __syncthreads();

    const int tc = t & 15;   // 16 col-groups x 4 cols = 64 cols
    const int tr = t >> 4;   // 16 row-groups x 8 rows = 128 rows
    const int rowbase = rowblk * 128 + tr * 8;
    const int lastrow = nrows - 1;

    float4 acc[8];
#pragma unroll
    for (int i = 0; i < 8; ++i) acc[i] = make_float4(0.f, 0.f, 0.f, 0.f);

    const float4* __restrict__ X4 = reinterpret_cast<const float4*>(X);
    const float4* __restrict__ Wl4 = reinterpret_cast<const float4*>(Wlds);
    int rIdx[8];
#pragma unroll
    for (int i = 0; i < 8; ++i) {
        int r = rowbase + i;
        rIdx[i] = r < lastrow ? r : lastrow;
    }

    for (int kk = 0; kk < 32; ++kk) {
        float4 x[8];
#pragma unroll
        for (int i = 0; i < 8; ++i) x[i] = X4[(size_t)rIdx[i] * 32 + kk];
#pragma unroll
        for (int j = 0; j < 4; ++j) {
            const int k = kk * 4 + j;
            const float4 w0 = Wl4[k * 16 + tc];
#pragma unroll
            for (int i = 0; i < 8; ++i) {
                const float* xp = reinterpret_cast<const float*>(&x[i]);
                const float xs = xp[j];
                acc[i].x += xs * w0.x;
                acc[i].y += xs * w0.y;
                acc[i].z += xs * w0.z;
                acc[i].w += xs * w0.w;
            }
        }
    }

    // Slice-major store: global col = half*64 + tc*4 -> slab = col>>5, idx = (col&31)>>2.
    float4* __restrict__ C4 = reinterpret_cast<float4*>(C);
    const size_t slab = (size_t)nrows * 8;
    const int s0  = half * 2 + (tc >> 3);
    const int w0i = tc & 7;
#pragma unroll
    for (int i = 0; i < 8; ++i) {
        int r = rowbase + i;
        if (r < nrows) {
            const float nm = norm[r];
            float4 o = acc[i];
            o.x *= nm; o.y *= nm; o.z *= nm; o.w *= nm;
            C4[(size_t)s0 * slab + (size_t)r * 8 + w0i] = o;
        }
    }
}

// ---------- Column-sliced gather-aggregate, 128 B granules ----------
template <int F, bool RELU>
__global__ __launch_bounds__(256) void aggregate_sliced(const float* __restrict__ feat,
                                                        const int* __restrict__ rowptr,
                                                        const int* __restrict__ esrc,
                                                        const float* __restrict__ norm,
                                                        const float* __restrict__ b,
                                                        float* __restrict__ out,
                                                        int nnodes, int nchunks) {
    constexpr int NSLICE = F / 32;
    const int slice = blockIdx.x % NSLICE;
    const int chunk = blockIdx.x / NSLICE;
    const int span  = (nnodes + nchunks - 1) / nchunks;
    const int nbeg  = chunk * span;
    const int nend  = min(nnodes, nbeg + span);

    const int grp = threadIdx.x >> 3;
    const int l8  = threadIdx.x & 7;

    const float4* __restrict__ slab4 =
        reinterpret_cast<const float4*>(feat) + (size_t)slice * nnodes * 8;
    const float4 bb = reinterpret_cast<const float4*>(b)[slice * 8 + l8];

    for (int node = nbeg + grp; node < nend; node += 32) {
        const int beg = rowptr[node];
        const int end = rowptr[node + 1];

        float4 acc[8];
#pragma unroll
        for (int i = 0; i < 8; ++i) acc[i] = make_float4(0.f, 0.f, 0.f, 0.f);

        for (int e = beg; e < end; e += 8) {
            int idx[8];
#pragma unroll
            for (int i = 0; i < 8; ++i) {
                int ee = e + i;
                idx[i] = esrc[ee < end ? ee : end - 1];
            }
            float4 v[8];
#pragma unroll
            for (int i = 0; i < 8; ++i) v[i] = slab4[(size_t)idx[i] * 8 + l8];
#pragma unroll
            for (int i = 0; i < 8; ++i) {
                if (e + i < end) {
                    acc[i].x += v[i].x; acc[i].y += v[i].y;
                    acc[i].z += v[i].z; acc[i].w += v[i].w;
                }
            }
        }

        float4 a;
        a.x = ((acc[0].x + acc[1].x) + (acc[2].x + acc[3].x)) +
              ((acc[4].x + acc[5].x) + (acc[6].x + acc[7].x));
        a.y = ((acc[0].y + acc[1].y) + (acc[2].y + acc[3].y)) +
              ((acc[4].y + acc[5].y) + (acc[6].y + acc[7].y));
        a.z = ((acc[0].z + acc[1].z) + (acc[2].z + acc[3].z)) +
              ((acc[4].z + acc[5].z) + (acc[6].z + acc[7].z));
        a.w = ((acc[0].w + acc[1].w) + (acc[2].w + acc[3].w)) +
              ((acc[4].w + acc[5].w) + (acc[6].w + acc[7].w));

        const float nm = norm[node];
        float4 o;
        o.x = a.x * nm + bb.x;
        o.y = a.y * nm + bb.y;
        o.z = a.z * nm + bb.z;
        o.w = a.w * nm + bb.w;
        if (RELU) {
            o.x = fmaxf(o.x, 0.f); o.y = fmaxf(o.y, 0.f);
            o.z = fmaxf(o.z, 0.f); o.w = fmaxf(o.w, 0.f);
        }
        reinterpret_cast<float4*>(out)[(size_t)node * (F / 4) + slice * 8 + l8] = o;
    }
}

extern "C" void kernel_launch(void* const* d_in, const int* in_sizes, int n_in,
                              void* d_out, int out_size, void* d_ws, size_t ws_size,
                              hipStream_t stream) {
    const float* features = (const float*)d_in[0];
    const int*   src      = (const int*)d_in[1];
    const int*   dst      = (const int*)d_in[2];
    const float* W1 = (const float*)d_in[3];
    const float* b1 = (const float*)d_in[4];
    const float* W2 = (const float*)d_in[5];
    const float* b2 = (const float*)d_in[6];
    const float* W3 = (const float*)d_in[7];
    const float* b3 = (const float*)d_in[8];
    float* out = (float*)d_out;

    auto align256 = [](size_t x) { return (x + 255) / 256 * 256; };
    char* ws = (char*)d_ws;
    size_t off = 0;
    float* norm    = (float*)(ws + off); off += align256((size_t)N_NODES * 4);
    int*   bcnt    = (int*)(ws + off);   off += align256((size_t)NBUCKET * 4);
    int*   bbase   = (int*)(ws + off);   off += align256((size_t)NBUCKET * 4);
    int*   bcursor = (int*)(ws + off);   off += align256((size_t)NBUCKET * 4);
    int*   rowptr  = (int*)(ws + off);   off += align256(((size_t)N_NODES + 1) * 4);
    int*   etmp    = (int*)(ws + off);   off += align256((size_t)N_EDGES * 4);
    int*   esrc    = (int*)(ws + off);   off += align256((size_t)N_EDGES * 4);
    float* buf0    = (float*)(ws + off); off += (size_t)N_NODES * 128 * 4;
    float* buf1    = (float*)(ws + off);

    const int row_blks = (N_NODES + 127) / 128;  // 391
    const int chunks = (N_NODES + 95) / 96;      // span 96 -> 3 nodes per 8-lane group

    // ---- CSR build (bucket counting sort) + norm ----
    hipMemsetAsync(bcnt, 0, (size_t)NBUCKET * 4, stream);
    bucket_count<<<EDGE_BLKS, 256, 0, stream>>>(dst, bcnt, N_EDGES);
    bucket_scan<<<1, 256, 0, stream>>>(bcnt, bbase, bcursor, NBUCKET);
    partition_kernel<<<EDGE_BLKS, 256, 0, stream>>>(src, dst, bcursor, etmp, N_EDGES);
    bucket_build<<<NBUCKET, 256, 0, stream>>>(etmp, bbase, rowptr, esrc, norm,
                                              N_NODES, NBUCKET, N_EDGES);

    // ---- Layer 1 ----
    gemm_rownorm<128><<<row_blks * 2, 256, 0, stream>>>(features, W1, norm, buf0, N_NODES);
    aggregate_sliced<128, true><<<chunks * 4, 256, 0, stream>>>(buf0, rowptr, esrc, norm, b1, buf1, N_NODES, chunks);

    // ---- Layer 2 ----
    gemm_rownorm<128><<<row_blks * 2, 256, 0, stream>>>(buf1, W2, norm, buf0, N_NODES);
    aggregate_sliced<128, true><<<chunks * 4, 256, 0, stream>>>(buf0, rowptr, esrc, norm, b2, buf1, N_NODES, chunks);

    // ---- Layer 3 (64 cols) ----
    gemm_rownorm<64><<<row_blks, 256, 0, stream>>>(buf1, W3, norm, buf0, N_NODES);
    aggregate_sliced<64, false><<<chunks * 2, 256, 0, stream>>>(buf0, rowptr, esrc, norm, b3, out, N_NODES, chunks);
}

// Round 12
// 245.088 us; speedup vs baseline: 1.0531x; 1.0531x over previous
//
#include <hip/hip_runtime.h>

#define N_NODES 50000
#define N_EDGES 800000
#define NBUCKET 196           // ceil(N_NODES / 256); bucket b = dst in [b*256,(b+1)*256)
#define EPB 4096              // edges per block in bucket_count / partition (16/thread)
#define EDGE_BLKS ((N_EDGES + EPB - 1) / EPB)  // 196

__device__ __forceinline__ int wave_incl_scan(int v, int lane) {
#pragma unroll
    for (int off = 1; off < 64; off <<= 1) {
        int t = __shfl_up(v, off, 64);
        if (lane >= off) v += t;
    }
    return v;
}

// ---------- CSR build via bucket counting sort ----------

__global__ __launch_bounds__(256) void bucket_count(const int* __restrict__ dst,
                                                    int* __restrict__ bcnt, int nedges) {
    __shared__ int h[NBUCKET];
    for (int i = threadIdx.x; i < NBUCKET; i += 256) h[i] = 0;
    __syncthreads();
    const int eb = blockIdx.x * EPB;
#pragma unroll
    for (int i = 0; i < 16; ++i) {
        int e = eb + i * 256 + threadIdx.x;
        if (e < nedges) atomicAdd(&h[dst[e] >> 8], 1);
    }
    __syncthreads();
    for (int i = threadIdx.x; i < NBUCKET; i += 256)
        if (h[i]) atomicAdd(&bcnt[i], h[i]);
}

__global__ __launch_bounds__(256) void bucket_scan(const int* __restrict__ bcnt,
                                                   int* __restrict__ bbase,
                                                   int* __restrict__ bcursor, int nb) {
    const int i = threadIdx.x;
    const int lane = i & 63;
    const int w = i >> 6;
    int v = (i < nb) ? bcnt[i] : 0;
    int s = wave_incl_scan(v, lane);
    __shared__ int ws[4];
    if (lane == 63) ws[w] = s;
    __syncthreads();
    int add = 0;
#pragma unroll
    for (int k = 0; k < 4; ++k)
        if (k < w) add += ws[k];
    if (i < nb) {
        int excl = s + add - v;
        bbase[i] = excl;
        bcursor[i] = excl;
    }
}

__global__ __launch_bounds__(256) void partition_kernel(const int* __restrict__ src,
                                                        const int* __restrict__ dst,
                                                        int* __restrict__ bcursor,
                                                        int* __restrict__ etmp, int nedges) {
    __shared__ int h[NBUCKET];
    __shared__ int rbase[NBUCKET];
    for (int i = threadIdx.x; i < NBUCKET; i += 256) h[i] = 0;
    __syncthreads();

    const int eb = blockIdx.x * EPB;
    int d[16], s[16];
    bool ok[16];
#pragma unroll
    for (int i = 0; i < 16; ++i) {
        int e = eb + i * 256 + threadIdx.x;
        ok[i] = e < nedges;
        d[i] = ok[i] ? dst[e] : 0;
        s[i] = ok[i] ? src[e] : 0;
        if (ok[i]) atomicAdd(&h[d[i] >> 8], 1);
    }
    __syncthreads();
    for (int i = threadIdx.x; i < NBUCKET; i += 256) {
        rbase[i] = h[i] ? atomicAdd(&bcursor[i], h[i]) : 0;
        h[i] = 0;  // reuse as local cursor
    }
    __syncthreads();
#pragma unroll
    for (int i = 0; i < 16; ++i) {
        if (ok[i]) {
            int b = d[i] >> 8;
            int pos = rbase[b] + atomicAdd(&h[b], 1);
            etmp[pos] = ((d[i] & 255) << 16) | s[i];
        }
    }
}

__global__ __launch_bounds__(256) void bucket_build(const int* __restrict__ etmp,
                                                    const int* __restrict__ bbase,
                                                    int* __restrict__ rowptr,
                                                    int* __restrict__ esrc,
                                                    float* __restrict__ norm,
                                                    int nnodes, int nbuckets, int nedges) {
    const int b = blockIdx.x;
    const int nodebase = b * 256;
    const int nloc = min(256, nnodes - nodebase);
    const int ebeg = bbase[b];
    const int eend = (b + 1 < nbuckets) ? bbase[b + 1] : nedges;

    __shared__ int h[256];
    __shared__ int cur[256];
    h[threadIdx.x] = 0;
    __syncthreads();

    for (int e = ebeg + threadIdx.x; e < eend; e += 256)
        atomicAdd(&h[etmp[e] >> 16], 1);
    __syncthreads();

    const int lane = threadIdx.x & 63;
    const int w = threadIdx.x >> 6;
    int v = h[threadIdx.x];
    int sc = wave_incl_scan(v, lane);
    __shared__ int ws[4];
    if (lane == 63) ws[w] = sc;
    __syncthreads();
    int add = 0;
#pragma unroll
    for (int k = 0; k < 4; ++k)
        if (k < w) add += ws[k];
    const int excl = sc + add - v;

    if (threadIdx.x < nloc) {
        rowptr[nodebase + threadIdx.x] = ebeg + excl;
        norm[nodebase + threadIdx.x] = v > 0 ? rsqrtf((float)v) : 0.0f;
        if (nodebase + threadIdx.x == nnodes - 1) rowptr[nnodes] = ebeg + excl + v;
    }
    cur[threadIdx.x] = excl;
    __syncthreads();

    for (int e = ebeg + threadIdx.x; e < eend; e += 256) {
        int rec = etmp[e];
        int pos = ebeg + atomicAdd(&cur[rec >> 16], 1);
        esrc[pos] = rec & 0xFFFF;
    }
}

// ---------- GEMM with output row-scale, W staged in LDS ----------
// Block = 64 rows x 64 cols (OUT=128 split into 2 col-halves).
// Grid ~1564 blocks -> ~6 blocks/CU (LDS allows 5) => latency hiding via TLP.
// Output: OUT/32 slabs of [nrows x 32] floats (slice-major, 128 B rows).
template <int OUT>
__global__ __launch_bounds__(256) void gemm_rownorm(const float* __restrict__ X,
                                                    const float* __restrict__ W,
                                                    const float* __restrict__ norm,
                                                    float* __restrict__ C, int nrows) {
    constexpr int NHALF = OUT / 64;          // 2 for OUT=128, 1 for OUT=64
    const int half = (NHALF > 1) ? (blockIdx.x % NHALF) : 0;
    const int rowblk = blockIdx.x / NHALF;

    __shared__ float Wlds[128 * 64];  // 32 KB

    const int t = threadIdx.x;

    // Stage this half's W columns: W[k][half*64 .. half*64+63], 2048 float4s.
    {
        const float4* __restrict__ Wg = reinterpret_cast<const float4*>(W);
        float4* Wl = reinterpret_cast<float4*>(Wlds);
#pragma unroll
        for (int s = 0; s < 8; ++s) {
            int idx = s * 256 + t;          // 0..2047
            int k  = idx >> 4;              // W row
            int cg = idx & 15;              // float4 within 64 cols
            Wl[idx] = Wg[k * (OUT / 4) + half * 16 + cg];
        }
    }
    __syncthreads();

    const int tc = t & 15;   // 16 col-groups x 4 cols = 64 cols
    const int tr = t >> 4;   // 16 row-groups x 4 rows = 64 rows
    const int rowbase = rowblk * 64 + tr * 4;
    const int lastrow = nrows - 1;

    float4 acc[4];
#pragma unroll
    for (int i = 0; i < 4; ++i) acc[i] = make_float4(0.f, 0.f, 0.f, 0.f);

    const float4* __restrict__ X4 = reinterpret_cast<const float4*>(X);
    const float4* __restrict__ Wl4 = reinterpret_cast<const float4*>(Wlds);
    int rIdx[4];
#pragma unroll
    for (int i = 0; i < 4; ++i) {
        int r = rowbase + i;
        rIdx[i] = r < lastrow ? r : lastrow;
    }

    for (int kk = 0; kk < 32; ++kk) {
        float4 x[4];
#pragma unroll
        for (int i = 0; i < 4; ++i) x[i] = X4[(size_t)rIdx[i] * 32 + kk];
#pragma unroll
        for (int j = 0; j < 4; ++j) {
            const int k = kk * 4 + j;
            const float4 w0 = Wl4[k * 16 + tc];
#pragma unroll
            for (int i = 0; i < 4; ++i) {
                const float* xp = reinterpret_cast<const float*>(&x[i]);
                const float xs = xp[j];
                acc[i].x += xs * w0.x;
                acc[i].y += xs * w0.y;
                acc[i].z += xs * w0.z;
                acc[i].w += xs * w0.w;
            }
        }
    }

    // Slice-major store: global col = half*64 + tc*4 -> slab = col>>5.
    float4* __restrict__ C4 = reinterpret_cast<float4*>(C);
    const size_t slab = (size_t)nrows * 8;
    const int s0  = half * 2 + (tc >> 3);
    const int w0i = tc & 7;
#pragma unroll
    for (int i = 0; i < 4; ++i) {
        int r = rowbase + i;
        if (r < nrows) {
            const float nm = norm[r];
            float4 o = acc[i];
            o.x *= nm; o.y *= nm; o.z *= nm; o.w *= nm;
            C4[(size_t)s0 * slab + (size_t)r * 8 + w0i] = o;
        }
    }
}

// ---------- Column-sliced gather-aggregate, 128 B granules ----------
template <int F, bool RELU>
__global__ __launch_bounds__(256) void aggregate_sliced(const float* __restrict__ feat,
                                                        const int* __restrict__ rowptr,
                                                        const int* __restrict__ esrc,
                                                        const float* __restrict__ norm,
                                                        const float* __restrict__ b,
                                                        float* __restrict__ out,
                                                        int nnodes, int nchunks) {
    constexpr int NSLICE = F / 32;
    const int slice = blockIdx.x % NSLICE;
    const int chunk = blockIdx.x / NSLICE;
    const int span  = (nnodes + nchunks - 1) / nchunks;
    const int nbeg  = chunk * span;
    const int nend  = min(nnodes, nbeg + span);

    const int grp = threadIdx.x >> 3;
    const int l8  = threadIdx.x & 7;

    const float4* __restrict__ slab4 =
        reinterpret_cast<const float4*>(feat) + (size_t)slice * nnodes * 8;
    const float4 bb = reinterpret_cast<const float4*>(b)[slice * 8 + l8];

    for (int node = nbeg + grp; node < nend; node += 32) {
        const int beg = rowptr[node];
        const int end = rowptr[node + 1];

        float4 acc[8];
#pragma unroll
        for (int i = 0; i < 8; ++i) acc[i] = make_float4(0.f, 0.f, 0.f, 0.f);

        for (int e = beg; e < end; e += 8) {
            int idx[8];
#pragma unroll
            for (int i = 0; i < 8; ++i) {
                int ee = e + i;
                idx[i] = esrc[ee < end ? ee : end - 1];
            }
            float4 v[8];
#pragma unroll
            for (int i = 0; i < 8; ++i) v[i] = slab4[(size_t)idx[i] * 8 + l8];
#pragma unroll
            for (int i = 0; i < 8; ++i) {
                if (e + i < end) {
                    acc[i].x += v[i].x; acc[i].y += v[i].y;
                    acc[i].z += v[i].z; acc[i].w += v[i].w;
                }
            }
        }

        float4 a;
        a.x = ((acc[0].x + acc[1].x) + (acc[2].x + acc[3].x)) +
              ((acc[4].x + acc[5].x) + (acc[6].x + acc[7].x));
        a.y = ((acc[0].y + acc[1].y) + (acc[2].y + acc[3].y)) +
              ((acc[4].y + acc[5].y) + (acc[6].y + acc[7].y));
        a.z = ((acc[0].z + acc[1].z) + (acc[2].z + acc[3].z)) +
              ((acc[4].z + acc[5].z) + (acc[6].z + acc[7].z));
        a.w = ((acc[0].w + acc[1].w) + (acc[2].w + acc[3].w)) +
              ((acc[4].w + acc[5].w) + (acc[6].w + acc[7].w));

        const float nm = norm[node];
        float4 o;
        o.x = a.x * nm + bb.x;
        o.y = a.y * nm + bb.y;
        o.z = a.z * nm + bb.z;
        o.w = a.w * nm + bb.w;
        if (RELU) {
            o.x = fmaxf(o.x, 0.f); o.y = fmaxf(o.y, 0.f);
            o.z = fmaxf(o.z, 0.f); o.w = fmaxf(o.w, 0.f);
        }
        reinterpret_cast<float4*>(out)[(size_t)node * (F / 4) + slice * 8 + l8] = o;
    }
}

extern "C" void kernel_launch(void* const* d_in, const int* in_sizes, int n_in,
                              void* d_out, int out_size, void* d_ws, size_t ws_size,
                              hipStream_t stream) {
    const float* features = (const float*)d_in[0];
    const int*   src      = (const int*)d_in[1];
    const int*   dst      = (const int*)d_in[2];
    const float* W1 = (const float*)d_in[3];
    const float* b1 = (const float*)d_in[4];
    const float* W2 = (const float*)d_in[5];
    const float* b2 = (const float*)d_in[6];
    const float* W3 = (const float*)d_in[7];
    const float* b3 = (const float*)d_in[8];
    float* out = (float*)d_out;

    auto align256 = [](size_t x) { return (x + 255) / 256 * 256; };
    char* ws = (char*)d_ws;
    size_t off = 0;
    float* norm    = (float*)(ws + off); off += align256((size_t)N_NODES * 4);
    int*   bcnt    = (int*)(ws + off);   off += align256((size_t)NBUCKET * 4);
    int*   bbase   = (int*)(ws + off);   off += align256((size_t)NBUCKET * 4);
    int*   bcursor = (int*)(ws + off);   off += align256((size_t)NBUCKET * 4);
    int*   rowptr  = (int*)(ws + off);   off += align256(((size_t)N_NODES + 1) * 4);
    int*   etmp    = (int*)(ws + off);   off += align256((size_t)N_EDGES * 4);
    int*   esrc    = (int*)(ws + off);   off += align256((size_t)N_EDGES * 4);
    float* buf0    = (float*)(ws + off); off += (size_t)N_NODES * 128 * 4;
    float* buf1    = (float*)(ws + off);

    const int row_blks = (N_NODES + 63) / 64;  // 782
    const int chunks = (N_NODES + 95) / 96;    // span 96 -> 3 nodes per 8-lane group

    // ---- CSR build (bucket counting sort) + norm ----
    hipMemsetAsync(bcnt, 0, (size_t)NBUCKET * 4, stream);
    bucket_count<<<EDGE_BLKS, 256, 0, stream>>>(dst, bcnt, N_EDGES);
    bucket_scan<<<1, 256, 0, stream>>>(bcnt, bbase, bcursor, NBUCKET);
    partition_kernel<<<EDGE_BLKS, 256, 0, stream>>>(src, dst, bcursor, etmp, N_EDGES);
    bucket_build<<<NBUCKET, 256, 0, stream>>>(etmp, bbase, rowptr, esrc, norm,
                                              N_NODES, NBUCKET, N_EDGES);

    // ---- Layer 1 ----
    gemm_rownorm<128><<<row_blks * 2, 256, 0, stream>>>(features, W1, norm, buf0, N_NODES);
    aggregate_sliced<128, true><<<chunks * 4, 256, 0, stream>>>(buf0, rowptr, esrc, norm, b1, buf1, N_NODES, chunks);

    // ---- Layer 2 ----
    gemm_rownorm<128><<<row_blks * 2, 256, 0, stream>>>(buf1, W2, norm, buf0, N_NODES);
    aggregate_sliced<128, true><<<chunks * 4, 256, 0, stream>>>(buf0, rowptr, esrc, norm, b2, buf1, N_NODES, chunks);

    // ---- Layer 3 (64 cols) ----
    gemm_rownorm<64><<<row_blks, 256, 0, stream>>>(buf1, W3, norm, buf0, N_NODES);
    aggregate_sliced<64, false><<<chunks * 2, 256, 0, stream>>>(buf0, rowptr, esrc, norm, b3, out, N_NODES, chunks);
}